// Round 8
// baseline (136.439 us; speedup 1.0000x reference)
//
#include <hip/hip_runtime.h>
#include <hip/hip_bf16.h>

#define D_K 576
#define NSLAB 18         // 576 / 32
#define LBDA_INV 2.0f    // 1/lbda, lbda=0.5
#define HALF_LBDA 0.5f
#define EPS 0.01f
#define DST 264          // Ds stride: 256 + 8 bf16 pad

typedef __attribute__((ext_vector_type(8))) short short8;
typedef __attribute__((ext_vector_type(4))) float f32x4;

__device__ inline float bf2f(unsigned short s) {
    return __uint_as_float(((unsigned)s) << 16);
}
// packed f32x2 -> bf16x2 (v_cvt_pk_bf16_f32 on gfx950), low half = x
__device__ inline unsigned pack_bf16(float x, float y) {
    __hip_bfloat162 h = __float22bfloat162_rn(float2{x, y});
    return *reinterpret_cast<unsigned*>(&h);
}

// ---------------- soft-min helpers (lbda = 0.5) ----------------
__device__ inline float softmin3(float a, float b, float c) {
    float mn = fminf(a, fminf(b, c));
    float s = __expf(-LBDA_INV * (a - mn)) + __expf(-LBDA_INV * (b - mn)) +
              __expf(-LBDA_INV * (c - mn));
    return mn - HALF_LBDA * __logf(s);
}
__device__ inline float softmin2(float a, float b) {
    float mn = fminf(a, b);
    float s = __expf(-LBDA_INV * (a - mn)) + __expf(-LBDA_INV * (b - mn));
    return mn - HALF_LBDA * __logf(s);
}

// OTAM DP over an 8x8 dist tile; element (l,s) at d[l*RS + s*CS].
template <int RS, int CS>
__device__ float otam_dp(const float* d) {
    float prev[10], cur[10];
    prev[0] = 0.f;
#pragma unroll
    for (int m = 1; m <= 8; ++m) prev[m] = prev[m - 1] + d[0 * RS + (m - 1) * CS];
    prev[9] = prev[8];  // pad col, d=0
#pragma unroll
    for (int l = 1; l < 8; ++l) {
        cur[0] = 0.f;
        cur[1] = d[l * RS + 0 * CS] + softmin3(prev[0], 0.f, prev[1]);
#pragma unroll
        for (int m = 2; m <= 8; ++m)
            cur[m] = d[l * RS + (m - 1) * CS] + softmin2(prev[m - 1], cur[m - 1]);
        cur[9] = softmin3(prev[8], cur[8], prev[9]);
#pragma unroll
        for (int m = 0; m < 10; ++m) prev[m] = cur[m];
    }
    return prev[9];
}

// =====================================================================================
// Single kernel, 512 blocks = 256 qblks (64 q-rows) x 2 s-halves (256 s-rows).
// qry f32 is read ONCE chip-wide (siblings b, b+256 share an XCD); the replicated
// B-half read (590 KB f32) is L2-resident. Per K-slab: f32 -> bf16 into chunk-major
// XOR-swizzled LDS, norms accumulated in registers, MFMA from LDS; then epilogue + DP.
// LDS chunk (c_in, r) of a slab at ushort offset (c_in*R + (r ^ (c_in<<1)))*8.
// =====================================================================================
__global__ __launch_bounds__(256, 2) void fused_kernel(
        const float* __restrict__ sup, const float* __restrict__ qry,
        float* __restrict__ out) {
    __shared__ unsigned short smem[64 * DST];   // 33.8 KB; K-loop aliases first 20 KB
    __shared__ float qn_l[64], sn_l[256];
    unsigned short* As = smem;                  // 64x32 bf16 slab  (4 KB)
    unsigned short* Bs = smem + 2048;           // 256x32 bf16 slab (16 KB)
    unsigned short* Ds = smem;

    const int t = threadIdx.x;
    const int b = blockIdx.x;
    const int shalf = b >> 8;                 // 0..1 (siblings b, b+256: same XCD)
    const int qblk = b & 255;                 // 0..255

    const float* Ag = qry + (size_t)qblk * 64 * D_K;
    const float* Bg = sup + (size_t)shalf * 256 * D_K;

    const int lane = t & 63;
    const int wave = t >> 6;                  // wave owns s-cols [wave*64, +64)
    const int col16 = lane & 15, quad = lane >> 4;

    f32x4 acc[4][4];
#pragma unroll
    for (int i = 0; i < 4; ++i)
#pragma unroll
        for (int j = 0; j < 4; ++j) acc[i][j] = (f32x4){0.f, 0.f, 0.f, 0.f};

    // staging geometry: thread covers rows {i*32 + (t>>3)}, col-octet (t&7) of each slab
    const int srow = t >> 3, scol = t & 7;
    const int c_in = scol >> 1, half = scol & 1, swz = c_in << 1;
    float sq_a[2] = {0.f, 0.f};
    float sq_b[8] = {0.f, 0.f, 0.f, 0.f, 0.f, 0.f, 0.f, 0.f};

    // fragment offsets (ushorts): read-side applies the same XOR swizzle (c_in = quad)
    int aoff[4], boff[4];
#pragma unroll
    for (int mt = 0; mt < 4; ++mt) {
        int m = mt * 16 + col16;                       // 0..63
        aoff[mt] = (quad * 64 + (m ^ (quad << 1))) * 8;
    }
#pragma unroll
    for (int nt = 0; nt < 4; ++nt) {
        int n = wave * 64 + nt * 16 + col16;           // 0..255
        boff[nt] = (quad * 256 + (n ^ (quad << 1))) * 8;
    }

    for (int j = 0; j < NSLAB; ++j) {
        const int kbase = j * 32 + scol * 4;
        float4 va[2], vb[8];
#pragma unroll
        for (int i = 0; i < 2; ++i)
            va[i] = *(const float4*)(Ag + (size_t)(i * 32 + srow) * D_K + kbase);
#pragma unroll
        for (int i = 0; i < 8; ++i)
            vb[i] = *(const float4*)(Bg + (size_t)(i * 32 + srow) * D_K + kbase);
#pragma unroll
        for (int i = 0; i < 2; ++i) {
            int r = i * 32 + srow;
            sq_a[i] += va[i].x * va[i].x + va[i].y * va[i].y +
                       va[i].z * va[i].z + va[i].w * va[i].w;
            int off = (c_in * 64 + (r ^ swz)) * 8 + half * 4;
            *(uint2*)(As + off) = uint2{pack_bf16(va[i].x, va[i].y),
                                        pack_bf16(va[i].z, va[i].w)};
        }
#pragma unroll
        for (int i = 0; i < 8; ++i) {
            int r = i * 32 + srow;
            sq_b[i] += vb[i].x * vb[i].x + vb[i].y * vb[i].y +
                       vb[i].z * vb[i].z + vb[i].w * vb[i].w;
            int off = (c_in * 256 + (r ^ swz)) * 8 + half * 4;
            *(uint2*)(Bs + off) = uint2{pack_bf16(vb[i].x, vb[i].y),
                                        pack_bf16(vb[i].z, vb[i].w)};
        }
        __syncthreads();

        short8 af[4], bf[4];
#pragma unroll
        for (int mt = 0; mt < 4; ++mt) af[mt] = *(const short8*)(As + aoff[mt]);
#pragma unroll
        for (int nt = 0; nt < 4; ++nt) bf[nt] = *(const short8*)(Bs + boff[nt]);
#pragma unroll
        for (int mt = 0; mt < 4; ++mt)
#pragma unroll
            for (int nt = 0; nt < 4; ++nt)
                acc[mt][nt] = __builtin_amdgcn_mfma_f32_16x16x32_bf16(
                    af[mt], bf[nt], acc[mt][nt], 0, 0, 0);
        __syncthreads();
    }

    // norms: octet-reduce register partials (8 threads of an octet cover a row's cols)
#pragma unroll
    for (int i = 0; i < 2; ++i) {
        sq_a[i] += __shfl_down(sq_a[i], 4);
        sq_a[i] += __shfl_down(sq_a[i], 2);
        sq_a[i] += __shfl_down(sq_a[i], 1);
    }
#pragma unroll
    for (int i = 0; i < 8; ++i) {
        sq_b[i] += __shfl_down(sq_b[i], 4);
        sq_b[i] += __shfl_down(sq_b[i], 2);
        sq_b[i] += __shfl_down(sq_b[i], 1);
    }
    if ((t & 7) == 0) {
#pragma unroll
        for (int i = 0; i < 2; ++i) qn_l[i * 32 + srow] = sqrtf(sq_a[i]);
#pragma unroll
        for (int i = 0; i < 8; ++i) sn_l[i * 32 + srow] = sqrtf(sq_b[i]);
    }
    __syncthreads();

    // epilogue: dist = 1 - num/(|q||s|+eps) -> Ds (bf16); Ds aliases staging (barriered)
    // C/D layout: col(n) = lane&15, row(m) = quad*4 + reg
#pragma unroll
    for (int mt = 0; mt < 4; ++mt) {
#pragma unroll
        for (int reg = 0; reg < 4; ++reg) {
            int m = mt * 16 + quad * 4 + reg;          // 0..63
            float qv = qn_l[m];
#pragma unroll
            for (int nt = 0; nt < 4; ++nt) {
                int n = wave * 64 + nt * 16 + col16;   // 0..255
                float sv = sn_l[n];
                float dist = 1.f - acc[mt][nt][reg] / (qv * sv + EPS);
                unsigned p = pack_bf16(dist, 0.f);
                Ds[m * DST + n] = (unsigned short)(p & 0xFFFF);
            }
        }
    }
    __syncthreads();

    // DP phase: thread t owns pair (ql = t>>5 in 0..7, sl = t&31 in 0..31)
    const int ql = t >> 5, sl = t & 31;
    float d[64];
#pragma unroll
    for (int l = 0; l < 8; ++l) {
        short8 rowv = *(const short8*)(&Ds[(ql * 8 + l) * DST + sl * 8]);
#pragma unroll
        for (int jj = 0; jj < 8; ++jj) d[l * 8 + jj] = bf2f((unsigned short)rowv[jj]);
    }
    float r1 = otam_dp<8, 1>(d);   // dists
    float r2 = otam_dp<1, 8>(d);   // dists^T
    int qg = qblk * 8 + ql, sg = shalf * 32 + sl;
    out[qg * 64 + sg] = -(r1 + r2);
}

extern "C" void kernel_launch(void* const* d_in, const int* in_sizes, int n_in,
                              void* d_out, int out_size, void* d_ws, size_t ws_size,
                              hipStream_t stream) {
    const float* sup = (const float*)d_in[0];   // [64, 8, 576]
    const float* qry = (const float*)d_in[1];   // [2048, 8, 576]
    float* out = (float*)d_out;                 // [2048, 64]
    fused_kernel<<<dim3(512), dim3(256), 0, stream>>>(sup, qry, out);
}